// Round 6
// baseline (2039.284 us; speedup 1.0000x reference)
//
#include <hip/hip_runtime.h>
#include <cstddef>

#define TS 100000   // TIME_STEPS
#define NT 99999    // number of transition matrices / scan steps (TS-1)
#define HID 512

// Chunked-scan configuration: NC chunks of CHUNK_L outputs, BURN burn-in steps.
// Contraction per step: P-deviations x0.39, a-deviations x0.36 (from the
// S ~ 2I +- 0.6 stationary regime). BURN=96 => 1e-39 nominal / 1e-13 even at
// 3x-pessimistic contraction. Chunks whose tstart clamps to 1 are EXACT.
#define NC 2048
#define CHUNK_L 49        // 2048*49 = 100352 >= 100000
#define BURN 96

// ---------------------------------------------------------------------------
// Kernel 1: fused 3-layer MLP producing T_mats[t] (16x16 fp32) for t=0..NT-1.
// Block = 256 threads, 16 time-rows per block. h1/h2 staged in LDS (64 KiB ->
// 2 blocks/CU). W2/W3 are L2-resident (1.5 MB) and re-read per block.
// NOTE for profiling: layer-2/3 inner loops read h via UNIFORM LDS address
// (all 256 threads hit the same 16B) -> broadcast path, expected cheap. If
// VALUBusy comes back <60% with low HBM BW, that assumption failed; fix is
// W2-tiles->LDS / h->registers restructure or bf16x3 MFMA rewrite.
// ---------------------------------------------------------------------------
__global__ __launch_bounds__(256, 2)
void mlp_kernel(const float* __restrict__ Z,
                const float* __restrict__ W1, const float* __restrict__ b1,
                const float* __restrict__ W2, const float* __restrict__ b2,
                const float* __restrict__ W3, const float* __restrict__ b3,
                float* __restrict__ Tm) {
  __shared__ __align__(16) float h1[16][HID];   // 32 KiB
  __shared__ __align__(16) float h2[16][HID];   // 32 KiB
  // Z staging aliases the (not-yet-written) h2 buffer: 16*32 floats = 2 KiB.
  float (*zs)[32] = (float (*)[32])h2;

  const int tid = threadIdx.x;
  const int t0  = blockIdx.x << 4;

  // stage Z rows (guard the tail: rows >= NT unused)
  for (int idx = tid; idx < 16 * 32; idx += 256) {
    const int r = idx >> 5, c = idx & 31;
    const int t = t0 + r;
    zs[r][c] = (t < NT) ? Z[t * 32 + c] : 0.0f;
  }
  __syncthreads();

  // ---- layer 1: h1 = relu(Z @ W1 + b1). Each thread: cols tid and tid+256.
  {
    float la[16], lb[16];
    const float ba = b1[tid], bb = b1[tid + 256];
#pragma unroll
    for (int r = 0; r < 16; ++r) { la[r] = ba; lb[r] = bb; }
    for (int k = 0; k < 32; ++k) {
      const float wa = W1[k * HID + tid];
      const float wb = W1[k * HID + tid + 256];
#pragma unroll
      for (int r = 0; r < 16; ++r) {
        const float z = zs[r][k];            // LDS broadcast
        la[r] = fmaf(z, wa, la[r]);
        lb[r] = fmaf(z, wb, lb[r]);
      }
    }
    __syncthreads();
#pragma unroll
    for (int r = 0; r < 16; ++r) {
      h1[r][tid]       = fmaxf(la[r], 0.0f);
      h1[r][tid + 256] = fmaxf(lb[r], 0.0f);
    }
  }
  __syncthreads();

  // ---- layer 2: h2 = relu(h1 @ W2 + b2). Overwrites the (dead) zs alias.
  {
    float la[16], lb[16];
    const float ba = b2[tid], bb = b2[tid + 256];
#pragma unroll
    for (int r = 0; r < 16; ++r) { la[r] = ba; lb[r] = bb; }
    for (int k = 0; k < HID; k += 4) {
      const float wa0 = W2[(k + 0) * HID + tid];
      const float wa1 = W2[(k + 1) * HID + tid];
      const float wa2 = W2[(k + 2) * HID + tid];
      const float wa3 = W2[(k + 3) * HID + tid];
      const float wb0 = W2[(k + 0) * HID + tid + 256];
      const float wb1 = W2[(k + 1) * HID + tid + 256];
      const float wb2 = W2[(k + 2) * HID + tid + 256];
      const float wb3 = W2[(k + 3) * HID + tid + 256];
#pragma unroll
      for (int r = 0; r < 16; ++r) {
        const float4 h = *(const float4*)&h1[r][k];   // uniform-addr LDS b128
        la[r] = fmaf(h.x, wa0, la[r]);
        la[r] = fmaf(h.y, wa1, la[r]);
        la[r] = fmaf(h.z, wa2, la[r]);
        la[r] = fmaf(h.w, wa3, la[r]);
        lb[r] = fmaf(h.x, wb0, lb[r]);
        lb[r] = fmaf(h.y, wb1, lb[r]);
        lb[r] = fmaf(h.z, wb2, lb[r]);
        lb[r] = fmaf(h.w, wb3, lb[r]);
      }
    }
    __syncthreads();   // all h1 reads complete before h2 (zs-alias) writes
#pragma unroll
    for (int r = 0; r < 16; ++r) {
      h2[r][tid]       = fmaxf(la[r], 0.0f);
      h2[r][tid + 256] = fmaxf(lb[r], 0.0f);
    }
  }
  __syncthreads();

  // ---- layer 3: T = h2 @ W3 + b3   (256 output cols, 1 per thread)
  {
    float acc[16];
    const float bb = b3[tid];
#pragma unroll
    for (int r = 0; r < 16; ++r) acc[r] = bb;
    for (int k = 0; k < HID; k += 4) {
      const float w0 = W3[(k + 0) * 256 + tid];
      const float w1 = W3[(k + 1) * 256 + tid];
      const float w2 = W3[(k + 2) * 256 + tid];
      const float w3v = W3[(k + 3) * 256 + tid];
#pragma unroll
      for (int r = 0; r < 16; ++r) {
        const float4 h = *(const float4*)&h2[r][k];
        acc[r] = fmaf(h.x, w0, acc[r]);
        acc[r] = fmaf(h.y, w1, acc[r]);
        acc[r] = fmaf(h.z, w2, acc[r]);
        acc[r] = fmaf(h.w, w3v, acc[r]);
      }
    }
#pragma unroll
    for (int r = 0; r < 16; ++r)
      if (t0 + r < NT) Tm[(size_t)(t0 + r) * 256 + tid] = acc[r];
  }
}

// ---------------------------------------------------------------------------
// Kernel 2: chunked Kalman scan. One wave per chunk; chunk c owns outputs
// [c*CHUNK_L, min(+CHUNK_L, TS)), warm-started BURN steps early from (a=1,P=I).
//
// Lane layout: i = tid>>2 (row 0..15), cg = tid&3, c0 = 4*cg (col group).
// Lane owns A[i][c0..c0+3] of every 16x16 matrix in its registers.
// Element map: A[r][c] lives on lane (r<<2)|(c>>2), component c&3.
//
// Exact identities (H = Q = I):
//   S      = P_pred + I
//   P_upd  = I - K P_pred = 2I - P_pred - S^{-1}
//   K v    = P_pred (S^{-1} v)
// Gauss-Jordan inverse fully in registers via __shfl (no LDS, no barriers):
//   Aip = A[i][p]  <- lane (tid&~3)|(p>>2), comp p&3
//   Apr = A[p][c0.]<- lane (p<<2)|cg,       comps 0..3
//   piv = A[p][p]  <- lane (p<<2)|(p>>2),   comp p&3
// No pivoting: S ~ 2I +- 0.6 stationary -> cond(S) ~ 2. rcp is v_rcp_f32
// (1 ulp; same order as fp32 reassociation noise, damped by contraction).
// P_pred / S^{-1} rows are only consumed by their owning lane -> registers.
// ---------------------------------------------------------------------------
__global__ __launch_bounds__(64, 1)
void scan_chunk_kernel(const float* __restrict__ Tm, const float* __restrict__ Y,
                       float* __restrict__ out) {
  __shared__ __align__(16) float ST[16][16];  // T_t
  __shared__ __align__(16) float SX[16][16];  // P (updated state)
  __shared__ __align__(16) float SW[16][16];  // W = T @ P
  __shared__ __align__(16) float sa[16];      // a state
  __shared__ __align__(16) float sy[16];      // y_t
  __shared__ __align__(16) float sv[16];      // y - a_pred
  __shared__ __align__(16) float su[16];      // S^{-1} v
  __shared__ __align__(16) float sap[16];     // a_pred

  const int c = blockIdx.x;
  const int s = c * CHUNK_L;            // first owned output index
  if (s >= TS) return;
  const int e = (s + CHUNK_L < TS) ? (s + CHUNK_L) : TS;
  int tstart = s - BURN;
  if (tstart < 1) tstart = 1;           // clamp -> exact initial carry

  const int tid = threadIdx.x;
  const int i   = tid >> 2;
  const int c0  = (tid & 3) * 4;
  const int cg  = tid & 3;

  // init: P = I, a = ones (exact when tstart==1; warm start otherwise)
#pragma unroll
  for (int j = 0; j < 4; ++j) SX[i][c0 + j] = (i == c0 + j) ? 1.0f : 0.0f;
  if (tid < 16) {
    sa[tid] = 1.0f;
    if (c == 0) out[tid] = 1.0f;        // out row 0 = a0
  }
  __syncthreads();

  // prefetch for t = tstart
  float4 tr = *(const float4*)&Tm[(size_t)(tstart - 1) * 256 + tid * 4];
  float  yv = (tid < 16) ? Y[(size_t)tstart * 16 + tid] : 0.0f;

  for (int t = tstart; t < e; ++t) {
    const float4 tcur = tr;
    // stage T_t (= Tm[t-1]) and y_t
    *(float4*)&ST[i][c0] = tcur;
    if (tid < 16) sy[tid] = yv;
    __syncthreads();                                   // B1

    // prefetch next iteration's T and y (hides HBM latency under the body)
    if (t + 1 < e) {
      tr = *(const float4*)&Tm[(size_t)t * 256 + tid * 4];
      yv = (tid < 16) ? Y[(size_t)(t + 1) * 16 + tid] : 0.0f;
    }

    // ---- W = T @ X  (reads SX written last iter; protected by B1)
    float w0 = 0.f, w1 = 0.f, w2 = 0.f, w3 = 0.f;
#pragma unroll
    for (int k = 0; k < 16; ++k) {
      const float  a_ = ST[i][k];                      // 4-lane broadcast
      const float4 x4 = *(const float4*)&SX[k][c0];
      w0 = fmaf(a_, x4.x, w0);
      w1 = fmaf(a_, x4.y, w1);
      w2 = fmaf(a_, x4.z, w2);
      w3 = fmaf(a_, x4.w, w3);
    }
    *(float4*)&SW[i][c0] = make_float4(w0, w1, w2, w3);

    // ---- a_pred = T @ a  (each lane: 4-col partial, then 4-lane reduce)
    {
      const float4 a4 = *(const float4*)&sa[c0];
      float ap = tcur.x * a4.x + tcur.y * a4.y + tcur.z * a4.z + tcur.w * a4.w;
      ap += __shfl_xor(ap, 1);
      ap += __shfl_xor(ap, 2);
      if (cg == 0) { sap[i] = ap; sv[i] = sy[i] - ap; }
    }
    __syncthreads();                                   // B2

    // ---- P_pred = W @ T^T + I (registers only; own row i)
    float4 p4;
    {
      float p0 = (i == c0 + 0) ? 1.0f : 0.0f;
      float p1 = (i == c0 + 1) ? 1.0f : 0.0f;
      float p2 = (i == c0 + 2) ? 1.0f : 0.0f;
      float p3 = (i == c0 + 3) ? 1.0f : 0.0f;
#pragma unroll
      for (int k = 0; k < 16; k += 4) {
        const float4 wk = *(const float4*)&SW[i][k];   // row-sibling writes (B2)
        const float4 ta = *(const float4*)&ST[c0 + 0][k];
        const float4 tb = *(const float4*)&ST[c0 + 1][k];
        const float4 tc = *(const float4*)&ST[c0 + 2][k];
        const float4 td = *(const float4*)&ST[c0 + 3][k];
        p0 = fmaf(wk.x, ta.x, fmaf(wk.y, ta.y, fmaf(wk.z, ta.z, fmaf(wk.w, ta.w, p0))));
        p1 = fmaf(wk.x, tb.x, fmaf(wk.y, tb.y, fmaf(wk.z, tb.z, fmaf(wk.w, tb.w, p1))));
        p2 = fmaf(wk.x, tc.x, fmaf(wk.y, tc.y, fmaf(wk.z, tc.z, fmaf(wk.w, tc.w, p2))));
        p3 = fmaf(wk.x, td.x, fmaf(wk.y, td.y, fmaf(wk.z, td.z, fmaf(wk.w, td.w, p3))));
      }
      p4 = make_float4(p0, p1, p2, p3);
    }

    // ---- cur = row i of S = P_pred + I
    float4 cur;
    cur.x = p4.x + ((i == c0 + 0) ? 1.0f : 0.0f);
    cur.y = p4.y + ((i == c0 + 1) ? 1.0f : 0.0f);
    cur.z = p4.z + ((i == c0 + 2) ? 1.0f : 0.0f);
    cur.w = p4.w + ((i == c0 + 3) ? 1.0f : 0.0f);

    // ---- Gauss-Jordan inverse, registers + shuffles only (no barriers).
    // After p=15, cur = row i of S^{-1} (cols c0..c0+3).
#pragma unroll
    for (int p = 0; p < 16; ++p) {
      const int q    = p & 3;                 // component holding col p
      const int srcP = (p << 2) | cg;         // lane with A[p][c0..c0+3]
      const int srcA = (tid & ~3) | (p >> 2); // lane with A[i][p]
      const int srcD = (p << 2) | (p >> 2);   // lane with A[p][p]
      const float curq = (q == 0) ? cur.x : (q == 1) ? cur.y
                       : (q == 2) ? cur.z : cur.w;    // q is compile-time
      const float Aip = __shfl(curq, srcA);
      const float piv = __shfl(curq, srcD);
      float4 Apr;
      Apr.x = __shfl(cur.x, srcP);
      Apr.y = __shfl(cur.y, srcP);
      Apr.z = __shfl(cur.z, srcP);
      Apr.w = __shfl(cur.w, srcP);
      const float rp = __builtin_amdgcn_rcpf(piv);    // v_rcp_f32, 1 ulp
      float4 nw;
      if (i == p) {        // pivot row: scale (Apr == cur here)
        nw.x = Apr.x * rp; nw.y = Apr.y * rp;
        nw.z = Apr.z * rp; nw.w = Apr.w * rp;
      } else {             // eliminate
        const float f = Aip * rp;
        nw.x = fmaf(-f, Apr.x, cur.x);
        nw.y = fmaf(-f, Apr.y, cur.y);
        nw.z = fmaf(-f, Apr.z, cur.z);
        nw.w = fmaf(-f, Apr.w, cur.w);
      }
      if (cg == (p >> 2)) {                   // pivot-column fix-up (static comp)
        const float repl = (i == p) ? rp : -(Aip * rp);
        if      (q == 0) nw.x = repl;
        else if (q == 1) nw.y = repl;
        else if (q == 2) nw.z = repl;
        else             nw.w = repl;
      }
      cur = nw;
    }

    // ---- u = S^{-1} v ; X = 2I - P_pred - S^{-1}
    {
      const float4 v4 = *(const float4*)&sv[c0];       // written pre-B2
      float up = cur.x * v4.x + cur.y * v4.y + cur.z * v4.z + cur.w * v4.w;
      up += __shfl_xor(up, 1);
      up += __shfl_xor(up, 2);
      if (cg == 0) su[i] = up;

      float4 nx;
      nx.x = ((i == c0 + 0) ? 2.0f : 0.0f) - p4.x - cur.x;
      nx.y = ((i == c0 + 1) ? 2.0f : 0.0f) - p4.y - cur.y;
      nx.z = ((i == c0 + 2) ? 2.0f : 0.0f) - p4.z - cur.z;
      nx.w = ((i == c0 + 3) ? 2.0f : 0.0f) - p4.w - cur.w;
      *(float4*)&SX[i][c0] = nx;                       // read next iter (B1)
    }
    __syncthreads();                                   // B3

    // ---- a = a_pred + P_pred @ u ; emit if within owned range
    {
      const float4 u4 = *(const float4*)&su[c0];
      float wp = p4.x * u4.x + p4.y * u4.y + p4.z * u4.z + p4.w * u4.w;
      wp += __shfl_xor(wp, 1);
      wp += __shfl_xor(wp, 2);
      if (cg == 0) sa[i] = sap[i] + wp;
    }
    __syncthreads();                                   // B4
    if (t >= s && tid < 16) out[(size_t)t * 16 + tid] = sa[tid];
    // loop-top B1 protects ST/sy restage vs this iteration's readers
  }
}

// ---------------------------------------------------------------------------
extern "C" void kernel_launch(void* const* d_in, const int* in_sizes, int n_in,
                              void* d_out, int out_size, void* d_ws, size_t ws_size,
                              hipStream_t stream) {
  const float* Y  = (const float*)d_in[0];
  const float* Z  = (const float*)d_in[1];
  const float* W1 = (const float*)d_in[2];
  const float* b1 = (const float*)d_in[3];
  const float* W2 = (const float*)d_in[4];
  const float* b2 = (const float*)d_in[5];
  const float* W3 = (const float*)d_in[6];
  const float* b3 = (const float*)d_in[7];
  float* out = (float*)d_out;
  float* Tm  = (float*)d_ws;   // NT * 256 * 4 B = 102.4 MB scratch

  hipLaunchKernelGGL(mlp_kernel, dim3((NT + 15) / 16), dim3(256), 0, stream,
                     Z, W1, b1, W2, b2, W3, b3, Tm);
  hipLaunchKernelGGL(scan_chunk_kernel, dim3(NC), dim3(64), 0, stream,
                     Tm, Y, out);
}

// Round 8
// 1887.133 us; speedup vs baseline: 1.0806x; 1.0806x over previous
//
#include <hip/hip_runtime.h>
#include <cstddef>

#define TS 100000   // TIME_STEPS
#define NT 99999    // number of transition matrices / scan steps (TS-1)
#define HID 512

// Chunked-scan configuration. Round-6 PASSED (absmax = 1 bf16 ulp) at
// BURN=96/NC=2048 with no chunk-boundary artifacts -> contraction confirmed.
// BURN=71 at 3x-pessimistic rate still gives 1.6e-7 warm-start error.
#define NC 4096
#define CHUNK_L 25        // 4096*25 = 102400 >= 100000 (chunks >=4000 idle)
#define BURN 71

typedef __attribute__((ext_vector_type(8))) short bf16x8;   // 8 bf16 in 4 VGPRs
typedef __attribute__((ext_vector_type(4))) float f32x4;

// Truncation split: x = hi + lo + eps, |eps| <= 2^-16 |x|.
__device__ inline short bf16_hi(float x) {
  return (short)(__float_as_uint(x) >> 16);
}
__device__ inline float bf16_hi_f(float x) {
  return __uint_as_float(__float_as_uint(x) & 0xffff0000u);
}
__device__ inline void split2(float x, short& h, short& s) {
  unsigned u = __float_as_uint(x);
  h = (short)(u >> 16);
  float rem = x - __uint_as_float(u & 0xffff0000u);
  s = (short)(__float_as_uint(rem) >> 16);
}

// ---------------------------------------------------------------------------
// Weight pre-swizzle: fp32 W[K][N] -> hi/lo bf16 in MFMA B-fragment order:
//   dst[((nt*KT + kt)*64 + lane)*8 + j] = W[kt*32 + (lane>>4)*8 + j][nt*16 + (lane&15)]
// Consumer loads one 16B dwordx4 per fragment. The (lane>>4,j)->k map only
// needs to be CONSISTENT with the A-side (k-permutations cancel in the dot;
// HW A/B k-maps are the same symmetric fragment design for 16x16x32).
// Runs every launch (ws re-poisoned); ~1.6 MB total, trivial cost.
// ---------------------------------------------------------------------------
__global__ void wsplit_kernel(const float* __restrict__ W, short* __restrict__ Whi,
                              short* __restrict__ Wlo, int K, int N) {
  int e = blockIdx.x * 256 + threadIdx.x;
  if (e >= K * N) return;
  const int j  = e & 7;
  const int l  = (e >> 3) & 63;
  const int r  = e >> 9;
  const int KT = K >> 5;
  const int kt = r % KT;
  const int nt = r / KT;
  const int k   = kt * 32 + (l >> 4) * 8 + j;
  const int col = nt * 16 + (l & 15);
  const float w = W[(size_t)k * N + col];
  Whi[e] = bf16_hi(w);
  Wlo[e] = bf16_hi(w - bf16_hi_f(w));
}

// ---------------------------------------------------------------------------
// MFMA MLP: 512 threads = 8 waves = (4 row-groups x 2 col-halves), M-tile 64.
// fp32 emulated as 3 bf16 products (Ah*Bh + Al*Bh + Ah*Bl), error ~2^-16 rel.
// h1 stored pre-split (bf16 hi/lo) in LDS; layers 2+3 FUSED via a 64-col
// chunk buffer so h2 is never materialized. LDS = 148 KiB -> 1 block/CU,
// 8 waves = 2/SIMD. Weights stream from L2 (~1.6 MB hi+lo, resident).
// Row pitches (1040 B, 144 B) are both == 4 mod 32 dwords -> b128 reads land
// 8 dword-accesses/bank = wave64 minimum (conflict-free in throughput).
// MFMA frag maps: A row / B col = lane&15 (std); C/D n=lane&15,
// m=(lane>>4)*4+reg (m89-verified).
// ---------------------------------------------------------------------------
__global__ __launch_bounds__(512)
void mlp_mfma_kernel(const float* __restrict__ Z,
                     const short* __restrict__ W1hi, const short* __restrict__ W1lo,
                     const float* __restrict__ b1,
                     const short* __restrict__ W2hi, const short* __restrict__ W2lo,
                     const float* __restrict__ b2,
                     const short* __restrict__ W3hi, const short* __restrict__ W3lo,
                     const float* __restrict__ b3,
                     float* __restrict__ Tm) {
  __shared__ short h1hi[64][520];   // 65 KiB  (pad 520: 16B rows, +4-bank skew)
  __shared__ short h1lo[64][520];   // 65 KiB
  __shared__ short c2hi[64][72];    // 9 KiB   h2 chunk (64 k-cols)
  __shared__ short c2lo[64][72];    // 9 KiB

  const int tid  = threadIdx.x;
  const int l    = tid & 63;
  const int w    = tid >> 6;        // wave 0..7
  const int rg   = w >> 1;          // row-group 0..3 (16 rows each)
  const int ch   = w & 1;           // col-half
  const int lrow = l & 15;
  const int lk8  = (l >> 4) * 8;
  const int t0   = blockIdx.x * 64;

  // ---- layer 1: h1 = relu(Z @ W1 + b1), K=32 (single k-step)
  {
    int zr = t0 + rg * 16 + lrow;
    if (zr > NT - 1) zr = NT - 1;                    // tail clamp (discarded)
    const float* zp = Z + (size_t)zr * 32 + lk8;
    const float4 z0 = *(const float4*)zp;
    const float4 z1 = *(const float4*)(zp + 4);
    bf16x8 ah, al;
    short h, s;
    split2(z0.x, h, s); ah[0] = h; al[0] = s;
    split2(z0.y, h, s); ah[1] = h; al[1] = s;
    split2(z0.z, h, s); ah[2] = h; al[2] = s;
    split2(z0.w, h, s); ah[3] = h; al[3] = s;
    split2(z1.x, h, s); ah[4] = h; al[4] = s;
    split2(z1.y, h, s); ah[5] = h; al[5] = s;
    split2(z1.z, h, s); ah[6] = h; al[6] = s;
    split2(z1.w, h, s); ah[7] = h; al[7] = s;

#pragma unroll
    for (int nt = 0; nt < 16; ++nt) {
      const int ntg = ch * 16 + nt;
      const size_t off = ((size_t)ntg * 64 + l) * 8;          // KT1 = 1
      const bf16x8 bh = *(const bf16x8*)(W1hi + off);
      const bf16x8 bl = *(const bf16x8*)(W1lo + off);
      f32x4 acc = {0.f, 0.f, 0.f, 0.f};
      acc = __builtin_amdgcn_mfma_f32_16x16x32_bf16(ah, bh, acc, 0, 0, 0);
      acc = __builtin_amdgcn_mfma_f32_16x16x32_bf16(al, bh, acc, 0, 0, 0);
      acc = __builtin_amdgcn_mfma_f32_16x16x32_bf16(ah, bl, acc, 0, 0, 0);
      const int col  = ntg * 16 + lrow;
      const float bias = b1[col];
#pragma unroll
      for (int m4 = 0; m4 < 4; ++m4) {
        const int row = rg * 16 + (l >> 4) * 4 + m4;
        const float v = fmaxf(acc[m4] + bias, 0.f);
        short hh, ll; split2(v, hh, ll);
        h1hi[row][col] = hh;
        h1lo[row][col] = ll;
      }
    }
  }
  __syncthreads();

  // ---- layers 2+3 fused over 8 chunks of 64 h2-columns
  f32x4 tacc[8];
#pragma unroll
  for (int nt = 0; nt < 8; ++nt) tacc[nt] = (f32x4){0.f, 0.f, 0.f, 0.f};

  for (int c = 0; c < 8; ++c) {
    // layer-2 partial: this wave's 16 rows x 32 cols (2 ntiles), full K=512
    f32x4 acc2[2] = {{0.f,0.f,0.f,0.f}, {0.f,0.f,0.f,0.f}};
#pragma unroll
    for (int kst = 0; kst < 16; ++kst) {
      const bf16x8 ah = *(const bf16x8*)&h1hi[rg * 16 + lrow][kst * 32 + lk8];
      const bf16x8 al = *(const bf16x8*)&h1lo[rg * 16 + lrow][kst * 32 + lk8];
#pragma unroll
      for (int nt = 0; nt < 2; ++nt) {
        const int ntg = c * 4 + ch * 2 + nt;
        const size_t off = (((size_t)ntg * 16 + kst) * 64 + l) * 8;
        const bf16x8 bh = *(const bf16x8*)(W2hi + off);
        const bf16x8 bl = *(const bf16x8*)(W2lo + off);
        acc2[nt] = __builtin_amdgcn_mfma_f32_16x16x32_bf16(ah, bh, acc2[nt], 0, 0, 0);
        acc2[nt] = __builtin_amdgcn_mfma_f32_16x16x32_bf16(al, bh, acc2[nt], 0, 0, 0);
        acc2[nt] = __builtin_amdgcn_mfma_f32_16x16x32_bf16(ah, bl, acc2[nt], 0, 0, 0);
      }
    }
    // epilogue -> chunk buffer (bias + relu + split)
#pragma unroll
    for (int nt = 0; nt < 2; ++nt) {
      const int lcol = ch * 32 + nt * 16 + lrow;   // 0..63 within chunk
      const float bias = b2[c * 64 + lcol];
#pragma unroll
      for (int m4 = 0; m4 < 4; ++m4) {
        const int row = rg * 16 + (l >> 4) * 4 + m4;
        const float v = fmaxf(acc2[nt][m4] + bias, 0.f);
        short hh, ll; split2(v, hh, ll);
        c2hi[row][lcol] = hh;
        c2lo[row][lcol] = ll;
      }
    }
    __syncthreads();   // chunk fully written before layer-3 reads

    // layer-3 partial: k-local 0..63 (2 k-steps), 8 ntiles into tacc
#pragma unroll
    for (int klc = 0; klc < 2; ++klc) {
      const bf16x8 ah = *(const bf16x8*)&c2hi[rg * 16 + lrow][klc * 32 + lk8];
      const bf16x8 al = *(const bf16x8*)&c2lo[rg * 16 + lrow][klc * 32 + lk8];
      const int kt = c * 2 + klc;
#pragma unroll
      for (int nt = 0; nt < 8; ++nt) {
        const int ntg = ch * 8 + nt;
        const size_t off = (((size_t)ntg * 16 + kt) * 64 + l) * 8;
        const bf16x8 bh = *(const bf16x8*)(W3hi + off);
        const bf16x8 bl = *(const bf16x8*)(W3lo + off);
        tacc[nt] = __builtin_amdgcn_mfma_f32_16x16x32_bf16(ah, bh, tacc[nt], 0, 0, 0);
        tacc[nt] = __builtin_amdgcn_mfma_f32_16x16x32_bf16(al, bh, tacc[nt], 0, 0, 0);
        tacc[nt] = __builtin_amdgcn_mfma_f32_16x16x32_bf16(ah, bl, tacc[nt], 0, 0, 0);
      }
    }
    __syncthreads();   // layer-3 reads done before next chunk overwrites
  }

  // ---- T epilogue: + b3, store
#pragma unroll
  for (int nt = 0; nt < 8; ++nt) {
    const int col  = ch * 128 + nt * 16 + lrow;
    const float bias = b3[col];
#pragma unroll
    for (int m4 = 0; m4 < 4; ++m4) {
      const int row = t0 + rg * 16 + (l >> 4) * 4 + m4;
      if (row < NT) Tm[(size_t)row * 256 + col] = tacc[nt][m4] + bias;
    }
  }
}

// ---------------------------------------------------------------------------
// Kernel 2: chunked Kalman scan (UNCHANGED from the round-6 PASSED version
// except NC/CHUNK_L/BURN). One wave per chunk; register/shuffle Gauss-Jordan.
// ---------------------------------------------------------------------------
__global__ __launch_bounds__(64, 1)
void scan_chunk_kernel(const float* __restrict__ Tm, const float* __restrict__ Y,
                       float* __restrict__ out) {
  __shared__ __align__(16) float ST[16][16];  // T_t
  __shared__ __align__(16) float SX[16][16];  // P (updated state)
  __shared__ __align__(16) float SW[16][16];  // W = T @ P
  __shared__ __align__(16) float sa[16];      // a state
  __shared__ __align__(16) float sy[16];      // y_t
  __shared__ __align__(16) float sv[16];      // y - a_pred
  __shared__ __align__(16) float su[16];      // S^{-1} v
  __shared__ __align__(16) float sap[16];     // a_pred

  const int c = blockIdx.x;
  const int s = c * CHUNK_L;
  if (s >= TS) return;
  const int e = (s + CHUNK_L < TS) ? (s + CHUNK_L) : TS;
  int tstart = s - BURN;
  if (tstart < 1) tstart = 1;

  const int tid = threadIdx.x;
  const int i   = tid >> 2;
  const int c0  = (tid & 3) * 4;
  const int cg  = tid & 3;

#pragma unroll
  for (int j = 0; j < 4; ++j) SX[i][c0 + j] = (i == c0 + j) ? 1.0f : 0.0f;
  if (tid < 16) {
    sa[tid] = 1.0f;
    if (c == 0) out[tid] = 1.0f;
  }
  __syncthreads();

  float4 tr = *(const float4*)&Tm[(size_t)(tstart - 1) * 256 + tid * 4];
  float  yv = (tid < 16) ? Y[(size_t)tstart * 16 + tid] : 0.0f;

  for (int t = tstart; t < e; ++t) {
    const float4 tcur = tr;
    *(float4*)&ST[i][c0] = tcur;
    if (tid < 16) sy[tid] = yv;
    __syncthreads();                                   // B1

    if (t + 1 < e) {
      tr = *(const float4*)&Tm[(size_t)t * 256 + tid * 4];
      yv = (tid < 16) ? Y[(size_t)(t + 1) * 16 + tid] : 0.0f;
    }

    float w0 = 0.f, w1 = 0.f, w2 = 0.f, w3 = 0.f;
#pragma unroll
    for (int k = 0; k < 16; ++k) {
      const float  a_ = ST[i][k];
      const float4 x4 = *(const float4*)&SX[k][c0];
      w0 = fmaf(a_, x4.x, w0);
      w1 = fmaf(a_, x4.y, w1);
      w2 = fmaf(a_, x4.z, w2);
      w3 = fmaf(a_, x4.w, w3);
    }
    *(float4*)&SW[i][c0] = make_float4(w0, w1, w2, w3);

    {
      const float4 a4 = *(const float4*)&sa[c0];
      float ap = tcur.x * a4.x + tcur.y * a4.y + tcur.z * a4.z + tcur.w * a4.w;
      ap += __shfl_xor(ap, 1);
      ap += __shfl_xor(ap, 2);
      if (cg == 0) { sap[i] = ap; sv[i] = sy[i] - ap; }
    }
    __syncthreads();                                   // B2

    float4 p4;
    {
      float p0 = (i == c0 + 0) ? 1.0f : 0.0f;
      float p1 = (i == c0 + 1) ? 1.0f : 0.0f;
      float p2 = (i == c0 + 2) ? 1.0f : 0.0f;
      float p3 = (i == c0 + 3) ? 1.0f : 0.0f;
#pragma unroll
      for (int k = 0; k < 16; k += 4) {
        const float4 wk = *(const float4*)&SW[i][k];
        const float4 ta = *(const float4*)&ST[c0 + 0][k];
        const float4 tb = *(const float4*)&ST[c0 + 1][k];
        const float4 tc = *(const float4*)&ST[c0 + 2][k];
        const float4 td = *(const float4*)&ST[c0 + 3][k];
        p0 = fmaf(wk.x, ta.x, fmaf(wk.y, ta.y, fmaf(wk.z, ta.z, fmaf(wk.w, ta.w, p0))));
        p1 = fmaf(wk.x, tb.x, fmaf(wk.y, tb.y, fmaf(wk.z, tb.z, fmaf(wk.w, tb.w, p1))));
        p2 = fmaf(wk.x, tc.x, fmaf(wk.y, tc.y, fmaf(wk.z, tc.z, fmaf(wk.w, tc.w, p2))));
        p3 = fmaf(wk.x, td.x, fmaf(wk.y, td.y, fmaf(wk.z, td.z, fmaf(wk.w, td.w, p3))));
      }
      p4 = make_float4(p0, p1, p2, p3);
    }

    float4 cur;
    cur.x = p4.x + ((i == c0 + 0) ? 1.0f : 0.0f);
    cur.y = p4.y + ((i == c0 + 1) ? 1.0f : 0.0f);
    cur.z = p4.z + ((i == c0 + 2) ? 1.0f : 0.0f);
    cur.w = p4.w + ((i == c0 + 3) ? 1.0f : 0.0f);

#pragma unroll
    for (int p = 0; p < 16; ++p) {
      const int q    = p & 3;
      const int srcP = (p << 2) | cg;
      const int srcA = (tid & ~3) | (p >> 2);
      const int srcD = (p << 2) | (p >> 2);
      const float curq = (q == 0) ? cur.x : (q == 1) ? cur.y
                       : (q == 2) ? cur.z : cur.w;
      const float Aip = __shfl(curq, srcA);
      const float piv = __shfl(curq, srcD);
      float4 Apr;
      Apr.x = __shfl(cur.x, srcP);
      Apr.y = __shfl(cur.y, srcP);
      Apr.z = __shfl(cur.z, srcP);
      Apr.w = __shfl(cur.w, srcP);
      const float rp = __builtin_amdgcn_rcpf(piv);
      float4 nw;
      if (i == p) {
        nw.x = Apr.x * rp; nw.y = Apr.y * rp;
        nw.z = Apr.z * rp; nw.w = Apr.w * rp;
      } else {
        const float f = Aip * rp;
        nw.x = fmaf(-f, Apr.x, cur.x);
        nw.y = fmaf(-f, Apr.y, cur.y);
        nw.z = fmaf(-f, Apr.z, cur.z);
        nw.w = fmaf(-f, Apr.w, cur.w);
      }
      if (cg == (p >> 2)) {
        const float repl = (i == p) ? rp : -(Aip * rp);
        if      (q == 0) nw.x = repl;
        else if (q == 1) nw.y = repl;
        else if (q == 2) nw.z = repl;
        else             nw.w = repl;
      }
      cur = nw;
    }

    {
      const float4 v4 = *(const float4*)&sv[c0];
      float up = cur.x * v4.x + cur.y * v4.y + cur.z * v4.z + cur.w * v4.w;
      up += __shfl_xor(up, 1);
      up += __shfl_xor(up, 2);
      if (cg == 0) su[i] = up;

      float4 nx;
      nx.x = ((i == c0 + 0) ? 2.0f : 0.0f) - p4.x - cur.x;
      nx.y = ((i == c0 + 1) ? 2.0f : 0.0f) - p4.y - cur.y;
      nx.z = ((i == c0 + 2) ? 2.0f : 0.0f) - p4.z - cur.z;
      nx.w = ((i == c0 + 3) ? 2.0f : 0.0f) - p4.w - cur.w;
      *(float4*)&SX[i][c0] = nx;
    }
    __syncthreads();                                   // B3

    {
      const float4 u4 = *(const float4*)&su[c0];
      float wp = p4.x * u4.x + p4.y * u4.y + p4.z * u4.z + p4.w * u4.w;
      wp += __shfl_xor(wp, 1);
      wp += __shfl_xor(wp, 2);
      if (cg == 0) sa[i] = sap[i] + wp;
    }
    __syncthreads();                                   // B4
    if (t >= s && tid < 16) out[(size_t)t * 16 + tid] = sa[tid];
  }
}

// ---------------------------------------------------------------------------
extern "C" void kernel_launch(void* const* d_in, const int* in_sizes, int n_in,
                              void* d_out, int out_size, void* d_ws, size_t ws_size,
                              hipStream_t stream) {
  const float* Y  = (const float*)d_in[0];
  const float* Z  = (const float*)d_in[1];
  const float* W1 = (const float*)d_in[2];
  const float* b1 = (const float*)d_in[3];
  const float* W2 = (const float*)d_in[4];
  const float* b2 = (const float*)d_in[5];
  const float* W3 = (const float*)d_in[6];
  const float* b3 = (const float*)d_in[7];
  float* out = (float*)d_out;

  char*  wsb = (char*)d_ws;
  float* Tm  = (float*)wsb;                         // NT*256*4 = 102,398,976 B
  const size_t tm_bytes = (size_t)NT * 256 * 4;
  short* W1hi = (short*)(wsb + tm_bytes);           // +1.64 MB of ws for weights
  short* W1lo = W1hi + 16384;
  short* W2hi = W1lo + 16384;
  short* W2lo = W2hi + 262144;
  short* W3hi = W2lo + 262144;
  short* W3lo = W3hi + 131072;

  hipLaunchKernelGGL(wsplit_kernel, dim3(64),   dim3(256), 0, stream, W1, W1hi, W1lo, 32, 512);
  hipLaunchKernelGGL(wsplit_kernel, dim3(1024), dim3(256), 0, stream, W2, W2hi, W2lo, 512, 512);
  hipLaunchKernelGGL(wsplit_kernel, dim3(512),  dim3(256), 0, stream, W3, W3hi, W3lo, 512, 256);

  hipLaunchKernelGGL(mlp_mfma_kernel, dim3((NT + 63) / 64), dim3(512), 0, stream,
                     Z, W1hi, W1lo, b1, W2hi, W2lo, b2, W3hi, W3lo, b3, Tm);

  hipLaunchKernelGGL(scan_chunk_kernel, dim3(NC), dim3(64), 0, stream, Tm, Y, out);
}

// Round 9
// 1348.918 us; speedup vs baseline: 1.5118x; 1.3990x over previous
//
#include <hip/hip_runtime.h>
#include <cstddef>

#define TS 100000   // TIME_STEPS
#define NT 99999    // number of transition matrices / scan steps (TS-1)
#define HID 512

// Chunked-scan configuration: REVERTED to the round-6 PASSED config
// (NC=4096 regressed scan ~420 -> ~760 us: +32% steps, worse Tm L2 reuse).
#define NC 2048
#define CHUNK_L 49        // 2048*49 = 100352 >= 100000
#define BURN 96

typedef __attribute__((ext_vector_type(8))) short bf16x8;   // 8 bf16 in 4 VGPRs
typedef __attribute__((ext_vector_type(4))) float f32x4;

// Truncation split: x = hi + lo + eps, |eps| <= 2^-16 |x|.
__device__ inline short bf16_hi(float x) {
  return (short)(__float_as_uint(x) >> 16);
}
__device__ inline float bf16_hi_f(float x) {
  return __uint_as_float(__float_as_uint(x) & 0xffff0000u);
}
__device__ inline void split2(float x, short& h, short& s) {
  unsigned u = __float_as_uint(x);
  h = (short)(u >> 16);
  float rem = x - __uint_as_float(u & 0xffff0000u);
  s = (short)(__float_as_uint(rem) >> 16);
}

// ---------------------------------------------------------------------------
// Weight pre-swizzle (UNCHANGED from round-8 PASSED): fp32 W[K][N] -> hi/lo
// bf16 in MFMA B-fragment order:
//   dst[((nt*KT + kt)*64 + l)*8 + j] = W[kt*32 + (l>>4)*8 + j][nt*16 + (l&15)]
// ---------------------------------------------------------------------------
__global__ void wsplit_kernel(const float* __restrict__ W, short* __restrict__ Whi,
                              short* __restrict__ Wlo, int K, int N) {
  int e = blockIdx.x * 256 + threadIdx.x;
  if (e >= K * N) return;
  const int j  = e & 7;
  const int l  = (e >> 3) & 63;
  const int r  = e >> 9;
  const int KT = K >> 5;
  const int kt = r % KT;
  const int nt = r / KT;
  const int k   = kt * 32 + (l >> 4) * 8 + j;
  const int col = nt * 16 + (l & 15);
  const float w = W[(size_t)k * N + col];
  Whi[e] = bf16_hi(w);
  Wlo[e] = bf16_hi(w - bf16_hi_f(w));
}

// ---------------------------------------------------------------------------
// MFMA MLP v2 — occupancy restructure of the round-8 PASSED kernel.
// Round-8 PMC: MfmaUtil 8.9%, VALUBusy 5.4%, HBM 1.5% -> latency-bound at
// 1 block/CU (148 KB LDS), 2 waves/SIMD. Fix:
//   * M-tile 32 (LDS 74 KB -> 2 blocks/CU, 4 waves/SIMD, 3125 blocks)
//   * waves = 2 row-groups x 4 col-quarters; tacc 8->4 (16 VGPRs freed)
//   * explicit next-kst register double-buffer of layer-2 weights
//   * __launch_bounds__(512,4) caps VGPR at 128 so 16 waves/CU fit
// Numerics IDENTICAL to round-8 (3-product bf16 split, same frag layout).
// ---------------------------------------------------------------------------
__global__ __launch_bounds__(512, 4)
void mlp_mfma_kernel(const float* __restrict__ Z,
                     const short* __restrict__ W1hi, const short* __restrict__ W1lo,
                     const float* __restrict__ b1,
                     const short* __restrict__ W2hi, const short* __restrict__ W2lo,
                     const float* __restrict__ b2,
                     const short* __restrict__ W3hi, const short* __restrict__ W3lo,
                     const float* __restrict__ b3,
                     float* __restrict__ Tm) {
  __shared__ short h1hi[32][520];   // 32.5 KiB (pitch 520: 16B rows, quad-spread)
  __shared__ short h1lo[32][520];   // 32.5 KiB
  __shared__ short c2hi[32][72];    // 4.5 KiB  h2 chunk (64 k-cols)
  __shared__ short c2lo[32][72];    // 4.5 KiB  -> total 74 KiB, 2 blocks/CU

  const int tid  = threadIdx.x;
  const int l    = tid & 63;
  const int w    = tid >> 6;        // wave 0..7
  const int rg   = w & 1;           // row-group 0..1 (16 rows each)
  const int cq   = w >> 1;          // col-quarter 0..3
  const int lrow = l & 15;
  const int lk8  = (l >> 4) * 8;
  const int t0   = blockIdx.x * 32;

  // ---- layer 1: h1 = relu(Z @ W1 + b1), K=32 (single k-step), 8 ntiles/wave
  {
    int zr = t0 + rg * 16 + lrow;
    if (zr > NT - 1) zr = NT - 1;                    // tail clamp (discarded)
    const float* zp = Z + (size_t)zr * 32 + lk8;
    const float4 z0 = *(const float4*)zp;
    const float4 z1 = *(const float4*)(zp + 4);
    bf16x8 ah, al;
    short h, s;
    split2(z0.x, h, s); ah[0] = h; al[0] = s;
    split2(z0.y, h, s); ah[1] = h; al[1] = s;
    split2(z0.z, h, s); ah[2] = h; al[2] = s;
    split2(z0.w, h, s); ah[3] = h; al[3] = s;
    split2(z1.x, h, s); ah[4] = h; al[4] = s;
    split2(z1.y, h, s); ah[5] = h; al[5] = s;
    split2(z1.z, h, s); ah[6] = h; al[6] = s;
    split2(z1.w, h, s); ah[7] = h; al[7] = s;

#pragma unroll
    for (int nt = 0; nt < 8; ++nt) {
      const int ntg = cq * 8 + nt;
      const size_t off = ((size_t)ntg * 64 + l) * 8;          // KT1 = 1
      const bf16x8 bh = *(const bf16x8*)(W1hi + off);
      const bf16x8 bl = *(const bf16x8*)(W1lo + off);
      f32x4 acc = {0.f, 0.f, 0.f, 0.f};
      acc = __builtin_amdgcn_mfma_f32_16x16x32_bf16(ah, bh, acc, 0, 0, 0);
      acc = __builtin_amdgcn_mfma_f32_16x16x32_bf16(al, bh, acc, 0, 0, 0);
      acc = __builtin_amdgcn_mfma_f32_16x16x32_bf16(ah, bl, acc, 0, 0, 0);
      const int col  = ntg * 16 + lrow;
      const float bias = b1[col];
#pragma unroll
      for (int m4 = 0; m4 < 4; ++m4) {
        const int row = rg * 16 + (l >> 4) * 4 + m4;
        const float v = fmaxf(acc[m4] + bias, 0.f);
        short hh, ll; split2(v, hh, ll);
        h1hi[row][col] = hh;
        h1lo[row][col] = ll;
      }
    }
  }
  __syncthreads();

  // ---- layers 2+3 fused over 8 chunks of 64 h2-columns
  f32x4 tacc[4];
#pragma unroll
  for (int nt = 0; nt < 4; ++nt) tacc[nt] = (f32x4){0.f, 0.f, 0.f, 0.f};

  for (int c = 0; c < 8; ++c) {
    // layer-2 partial: wave (rg,cq) -> ntile c*4+cq, its 16 rows, full K=512.
    // Weights double-buffered in registers: load kst+1 while MFMAing kst.
    f32x4 acc2 = {0.f, 0.f, 0.f, 0.f};
    const size_t base2 = (((size_t)(c * 4 + cq) * 16) * 64 + l) * 8;
    bf16x8 bh = *(const bf16x8*)(W2hi + base2);
    bf16x8 bl = *(const bf16x8*)(W2lo + base2);
#pragma unroll
    for (int kst = 0; kst < 16; ++kst) {
      bf16x8 nbh = bh, nbl = bl;
      if (kst < 15) {                                   // compile-time (unrolled)
        const size_t noff = base2 + (size_t)(kst + 1) * 512;   // 64 lanes * 8
        nbh = *(const bf16x8*)(W2hi + noff);
        nbl = *(const bf16x8*)(W2lo + noff);
      }
      const bf16x8 ah = *(const bf16x8*)&h1hi[rg * 16 + lrow][kst * 32 + lk8];
      const bf16x8 al = *(const bf16x8*)&h1lo[rg * 16 + lrow][kst * 32 + lk8];
      acc2 = __builtin_amdgcn_mfma_f32_16x16x32_bf16(ah, bh, acc2, 0, 0, 0);
      acc2 = __builtin_amdgcn_mfma_f32_16x16x32_bf16(al, bh, acc2, 0, 0, 0);
      acc2 = __builtin_amdgcn_mfma_f32_16x16x32_bf16(ah, bl, acc2, 0, 0, 0);
      bh = nbh; bl = nbl;
    }
    // epilogue -> chunk buffer (bias + relu + split)
    {
      const int lcol = cq * 16 + lrow;                 // 0..63 within chunk
      const float bias = b2[c * 64 + lcol];
#pragma unroll
      for (int m4 = 0; m4 < 4; ++m4) {
        const int row = rg * 16 + (l >> 4) * 4 + m4;
        const float v = fmaxf(acc2[m4] + bias, 0.f);
        short hh, ll; split2(v, hh, ll);
        c2hi[row][lcol] = hh;
        c2lo[row][lcol] = ll;
      }
    }
    __syncthreads();   // chunk fully written before layer-3 reads

    // layer-3 partial: k-local 0..63 (2 k-steps), wave's 4 ntiles (cq*4..+3)
#pragma unroll
    for (int klc = 0; klc < 2; ++klc) {
      const bf16x8 ah = *(const bf16x8*)&c2hi[rg * 16 + lrow][klc * 32 + lk8];
      const bf16x8 al = *(const bf16x8*)&c2lo[rg * 16 + lrow][klc * 32 + lk8];
      const int kt = c * 2 + klc;
#pragma unroll
      for (int nt = 0; nt < 4; ++nt) {
        const int ntg = cq * 4 + nt;
        const size_t off = (((size_t)ntg * 16 + kt) * 64 + l) * 8;
        const bf16x8 bh = *(const bf16x8*)(W3hi + off);
        const bf16x8 bl = *(const bf16x8*)(W3lo + off);
        tacc[nt] = __builtin_amdgcn_mfma_f32_16x16x32_bf16(ah, bh, tacc[nt], 0, 0, 0);
        tacc[nt] = __builtin_amdgcn_mfma_f32_16x16x32_bf16(al, bh, tacc[nt], 0, 0, 0);
        tacc[nt] = __builtin_amdgcn_mfma_f32_16x16x32_bf16(ah, bl, tacc[nt], 0, 0, 0);
      }
    }
    __syncthreads();   // layer-3 reads done before next chunk overwrites
  }

  // ---- T epilogue: + b3, store
#pragma unroll
  for (int nt = 0; nt < 4; ++nt) {
    const int col  = (cq * 4 + nt) * 16 + lrow;
    const float bias = b3[col];
#pragma unroll
    for (int m4 = 0; m4 < 4; ++m4) {
      const int row = t0 + rg * 16 + (l >> 4) * 4 + m4;
      if (row < NT) Tm[(size_t)row * 256 + col] = tacc[nt][m4] + bias;
    }
  }
}

// ---------------------------------------------------------------------------
// Kernel 2: chunked Kalman scan — BYTE-IDENTICAL to the round-6 PASSED
// version (register/shuffle GJ, NC=2048/CHUNK_L=49/BURN=96, scan ~420 us).
// ---------------------------------------------------------------------------
__global__ __launch_bounds__(64, 1)
void scan_chunk_kernel(const float* __restrict__ Tm, const float* __restrict__ Y,
                       float* __restrict__ out) {
  __shared__ __align__(16) float ST[16][16];  // T_t
  __shared__ __align__(16) float SX[16][16];  // P (updated state)
  __shared__ __align__(16) float SW[16][16];  // W = T @ P
  __shared__ __align__(16) float sa[16];      // a state
  __shared__ __align__(16) float sy[16];      // y_t
  __shared__ __align__(16) float sv[16];      // y - a_pred
  __shared__ __align__(16) float su[16];      // S^{-1} v
  __shared__ __align__(16) float sap[16];     // a_pred

  const int c = blockIdx.x;
  const int s = c * CHUNK_L;
  if (s >= TS) return;
  const int e = (s + CHUNK_L < TS) ? (s + CHUNK_L) : TS;
  int tstart = s - BURN;
  if (tstart < 1) tstart = 1;

  const int tid = threadIdx.x;
  const int i   = tid >> 2;
  const int c0  = (tid & 3) * 4;
  const int cg  = tid & 3;

#pragma unroll
  for (int j = 0; j < 4; ++j) SX[i][c0 + j] = (i == c0 + j) ? 1.0f : 0.0f;
  if (tid < 16) {
    sa[tid] = 1.0f;
    if (c == 0) out[tid] = 1.0f;
  }
  __syncthreads();

  float4 tr = *(const float4*)&Tm[(size_t)(tstart - 1) * 256 + tid * 4];
  float  yv = (tid < 16) ? Y[(size_t)tstart * 16 + tid] : 0.0f;

  for (int t = tstart; t < e; ++t) {
    const float4 tcur = tr;
    *(float4*)&ST[i][c0] = tcur;
    if (tid < 16) sy[tid] = yv;
    __syncthreads();                                   // B1

    if (t + 1 < e) {
      tr = *(const float4*)&Tm[(size_t)t * 256 + tid * 4];
      yv = (tid < 16) ? Y[(size_t)(t + 1) * 16 + tid] : 0.0f;
    }

    float w0 = 0.f, w1 = 0.f, w2 = 0.f, w3 = 0.f;
#pragma unroll
    for (int k = 0; k < 16; ++k) {
      const float  a_ = ST[i][k];
      const float4 x4 = *(const float4*)&SX[k][c0];
      w0 = fmaf(a_, x4.x, w0);
      w1 = fmaf(a_, x4.y, w1);
      w2 = fmaf(a_, x4.z, w2);
      w3 = fmaf(a_, x4.w, w3);
    }
    *(float4*)&SW[i][c0] = make_float4(w0, w1, w2, w3);

    {
      const float4 a4 = *(const float4*)&sa[c0];
      float ap = tcur.x * a4.x + tcur.y * a4.y + tcur.z * a4.z + tcur.w * a4.w;
      ap += __shfl_xor(ap, 1);
      ap += __shfl_xor(ap, 2);
      if (cg == 0) { sap[i] = ap; sv[i] = sy[i] - ap; }
    }
    __syncthreads();                                   // B2

    float4 p4;
    {
      float p0 = (i == c0 + 0) ? 1.0f : 0.0f;
      float p1 = (i == c0 + 1) ? 1.0f : 0.0f;
      float p2 = (i == c0 + 2) ? 1.0f : 0.0f;
      float p3 = (i == c0 + 3) ? 1.0f : 0.0f;
#pragma unroll
      for (int k = 0; k < 16; k += 4) {
        const float4 wk = *(const float4*)&SW[i][k];
        const float4 ta = *(const float4*)&ST[c0 + 0][k];
        const float4 tb = *(const float4*)&ST[c0 + 1][k];
        const float4 tc = *(const float4*)&ST[c0 + 2][k];
        const float4 td = *(const float4*)&ST[c0 + 3][k];
        p0 = fmaf(wk.x, ta.x, fmaf(wk.y, ta.y, fmaf(wk.z, ta.z, fmaf(wk.w, ta.w, p0))));
        p1 = fmaf(wk.x, tb.x, fmaf(wk.y, tb.y, fmaf(wk.z, tb.z, fmaf(wk.w, tb.w, p1))));
        p2 = fmaf(wk.x, tc.x, fmaf(wk.y, tc.y, fmaf(wk.z, tc.z, fmaf(wk.w, tc.w, p2))));
        p3 = fmaf(wk.x, td.x, fmaf(wk.y, td.y, fmaf(wk.z, td.z, fmaf(wk.w, td.w, p3))));
      }
      p4 = make_float4(p0, p1, p2, p3);
    }

    float4 cur;
    cur.x = p4.x + ((i == c0 + 0) ? 1.0f : 0.0f);
    cur.y = p4.y + ((i == c0 + 1) ? 1.0f : 0.0f);
    cur.z = p4.z + ((i == c0 + 2) ? 1.0f : 0.0f);
    cur.w = p4.w + ((i == c0 + 3) ? 1.0f : 0.0f);

#pragma unroll
    for (int p = 0; p < 16; ++p) {
      const int q    = p & 3;
      const int srcP = (p << 2) | cg;
      const int srcA = (tid & ~3) | (p >> 2);
      const int srcD = (p << 2) | (p >> 2);
      const float curq = (q == 0) ? cur.x : (q == 1) ? cur.y
                       : (q == 2) ? cur.z : cur.w;
      const float Aip = __shfl(curq, srcA);
      const float piv = __shfl(curq, srcD);
      float4 Apr;
      Apr.x = __shfl(cur.x, srcP);
      Apr.y = __shfl(cur.y, srcP);
      Apr.z = __shfl(cur.z, srcP);
      Apr.w = __shfl(cur.w, srcP);
      const float rp = __builtin_amdgcn_rcpf(piv);
      float4 nw;
      if (i == p) {
        nw.x = Apr.x * rp; nw.y = Apr.y * rp;
        nw.z = Apr.z * rp; nw.w = Apr.w * rp;
      } else {
        const float f = Aip * rp;
        nw.x = fmaf(-f, Apr.x, cur.x);
        nw.y = fmaf(-f, Apr.y, cur.y);
        nw.z = fmaf(-f, Apr.z, cur.z);
        nw.w = fmaf(-f, Apr.w, cur.w);
      }
      if (cg == (p >> 2)) {
        const float repl = (i == p) ? rp : -(Aip * rp);
        if      (q == 0) nw.x = repl;
        else if (q == 1) nw.y = repl;
        else if (q == 2) nw.z = repl;
        else             nw.w = repl;
      }
      cur = nw;
    }

    {
      const float4 v4 = *(const float4*)&sv[c0];
      float up = cur.x * v4.x + cur.y * v4.y + cur.z * v4.z + cur.w * v4.w;
      up += __shfl_xor(up, 1);
      up += __shfl_xor(up, 2);
      if (cg == 0) su[i] = up;

      float4 nx;
      nx.x = ((i == c0 + 0) ? 2.0f : 0.0f) - p4.x - cur.x;
      nx.y = ((i == c0 + 1) ? 2.0f : 0.0f) - p4.y - cur.y;
      nx.z = ((i == c0 + 2) ? 2.0f : 0.0f) - p4.z - cur.z;
      nx.w = ((i == c0 + 3) ? 2.0f : 0.0f) - p4.w - cur.w;
      *(float4*)&SX[i][c0] = nx;
    }
    __syncthreads();                                   // B3

    {
      const float4 u4 = *(const float4*)&su[c0];
      float wp = p4.x * u4.x + p4.y * u4.y + p4.z * u4.z + p4.w * u4.w;
      wp += __shfl_xor(wp, 1);
      wp += __shfl_xor(wp, 2);
      if (cg == 0) sa[i] = sap[i] + wp;
    }
    __syncthreads();                                   // B4
    if (t >= s && tid < 16) out[(size_t)t * 16 + tid] = sa[tid];
  }
}

// ---------------------------------------------------------------------------
extern "C" void kernel_launch(void* const* d_in, const int* in_sizes, int n_in,
                              void* d_out, int out_size, void* d_ws, size_t ws_size,
                              hipStream_t stream) {
  const float* Y  = (const float*)d_in[0];
  const float* Z  = (const float*)d_in[1];
  const float* W1 = (const float*)d_in[2];
  const float* b1 = (const float*)d_in[3];
  const float* W2 = (const float*)d_in[4];
  const float* b2 = (const float*)d_in[5];
  const float* W3 = (const float*)d_in[6];
  const float* b3 = (const float*)d_in[7];
  float* out = (float*)d_out;

  char*  wsb = (char*)d_ws;
  float* Tm  = (float*)wsb;                         // NT*256*4 = 102,398,976 B
  const size_t tm_bytes = (size_t)NT * 256 * 4;
  short* W1hi = (short*)(wsb + tm_bytes);           // +1.64 MB of ws for weights
  short* W1lo = W1hi + 16384;
  short* W2hi = W1lo + 16384;
  short* W2lo = W2hi + 262144;
  short* W3hi = W2lo + 262144;
  short* W3lo = W3hi + 131072;

  hipLaunchKernelGGL(wsplit_kernel, dim3(64),   dim3(256), 0, stream, W1, W1hi, W1lo, 32, 512);
  hipLaunchKernelGGL(wsplit_kernel, dim3(1024), dim3(256), 0, stream, W2, W2hi, W2lo, 512, 512);
  hipLaunchKernelGGL(wsplit_kernel, dim3(512),  dim3(256), 0, stream, W3, W3hi, W3lo, 512, 256);

  hipLaunchKernelGGL(mlp_mfma_kernel, dim3((NT + 31) / 32), dim3(512), 0, stream,
                     Z, W1hi, W1lo, b1, W2hi, W2lo, b2, W3hi, W3lo, b3, Tm);

  hipLaunchKernelGGL(scan_chunk_kernel, dim3(NC), dim3(64), 0, stream, Tm, Y, out);
}